// Round 1
// baseline (460.550 us; speedup 1.0000x reference)
//
#include <hip/hip_runtime.h>
#include <stdint.h>

#define DH 128   // D_IN == H == 128
#define NB 30    // num bases
#define NR 8     // num relations

// ---------- helpers ----------
static __device__ __forceinline__ unsigned short f2bf(float f) {
    unsigned u = __float_as_uint(f);
    u += 0x7fffu + ((u >> 16) & 1u);   // round-to-nearest-even
    return (unsigned short)(u >> 16);
}

// ---------- w_all[r] = sum_b comp[r,b]*basis[b]  (r==8 -> root) ----------
__global__ __launch_bounds__(128) void k_wall(const float* __restrict__ comp,
                                              const float* __restrict__ basis,
                                              const float* __restrict__ root,
                                              float* __restrict__ wall) {
    int o = threadIdx.x;    // 0..127
    int i = blockIdx.x;     // 0..127
    int r = blockIdx.y;     // 0..8
    float s;
    if (r == NR) {
        s = root[i * DH + o];
    } else {
        s = 0.f;
        #pragma unroll
        for (int b = 0; b < NB; ++b)
            s += comp[r * NB + b] * basis[((size_t)b * DH + i) * DH + o];
    }
    wall[((size_t)r * DH + i) * DH + o] = s;
}

// ---------- CSR build ----------
__global__ void k_hist(const int* __restrict__ dst, int E, int* __restrict__ deg) {
    int e = blockIdx.x * blockDim.x + threadIdx.x;
    if (e < E) atomicAdd(&deg[dst[e]], 1);
}

__global__ __launch_bounds__(1024) void k_scan1(const int* __restrict__ deg, int n, int total_n,
                                                int* __restrict__ offsets, int* __restrict__ partial) {
    __shared__ int s[1024];
    int tid = threadIdx.x;
    int i = blockIdx.x * 1024 + tid;
    int v = (i < n) ? deg[i] : 0;
    s[tid] = v;
    __syncthreads();
    for (int off = 1; off < 1024; off <<= 1) {
        int t = (tid >= off) ? s[tid - off] : 0;
        __syncthreads();
        s[tid] += t;
        __syncthreads();
    }
    if (i < total_n) offsets[i] = s[tid] - v;   // exclusive
    if (tid == 1023) partial[blockIdx.x] = s[1023];
}

__global__ void k_scan2(int* __restrict__ partial, int nb) {
    if (threadIdx.x == 0) {
        int run = 0;
        for (int b = 0; b < nb; ++b) { int t = partial[b]; partial[b] = run; run += t; }
    }
}

__global__ __launch_bounds__(1024) void k_scan3(int* __restrict__ offsets,
                                                const int* __restrict__ partial, int total_n) {
    int i = blockIdx.x * 1024 + threadIdx.x;
    if (i < total_n) offsets[i] += partial[blockIdx.x];
}

__global__ void k_scatter(const int* __restrict__ src, const int* __restrict__ dstA,
                          const int* __restrict__ etype, int E,
                          const int* __restrict__ offsets, int* __restrict__ cursor,
                          unsigned* __restrict__ sorted) {
    int e = blockIdx.x * blockDim.x + threadIdx.x;
    if (e >= E) return;
    int d = dstA[e];
    int pos = offsets[d] + atomicAdd(&cursor[d], 1);
    sorted[pos] = (unsigned)src[e] | ((unsigned)etype[e] << 17);  // src<2^17, type<8
}

// ---------- fp32 register-tiled GEMM: 64 rows x 128 cols per block ----------
// gemm1: grid (N/64, 9). r<8: xw[r] = X@W_r (store bf16). r==8: h = X@root + bias1 (fp32)
__global__ __launch_bounds__(256) void k_gemm1(const float* __restrict__ X,
                                               const float* __restrict__ wall,
                                               const float* __restrict__ bias1,
                                               int Nn,
                                               unsigned short* __restrict__ xw,
                                               float* __restrict__ h) {
    __shared__ float At[32][68];    // [kk][row], padded
    __shared__ float Bs[32][132];   // [kk][col], padded
    const int tid = threadIdx.x;
    const int tx = tid & 15;         // col group: cols tx*8..tx*8+7
    const int ty = tid >> 4;         // row group: rows ty*4..ty*4+3
    const int r  = blockIdx.y;
    const int rowbase = blockIdx.x * 64;
    const float* Wr = wall + (size_t)r * DH * DH;

    float acc[4][8];
    #pragma unroll
    for (int i = 0; i < 4; ++i)
        #pragma unroll
        for (int j = 0; j < 8; ++j) acc[i][j] = 0.f;

    for (int kt = 0; kt < 4; ++kt) {
        const int kb = kt * 32;
        __syncthreads();
        #pragma unroll
        for (int it = 0; it < 2; ++it) {            // A tile 64x32 (transposed into LDS)
            int s = tid + it * 256;
            int row = s >> 3, kq = s & 7;
            float4 v = *(const float4*)&X[(size_t)(rowbase + row) * DH + kb + kq * 4];
            At[kq * 4 + 0][row] = v.x;
            At[kq * 4 + 1][row] = v.y;
            At[kq * 4 + 2][row] = v.z;
            At[kq * 4 + 3][row] = v.w;
        }
        #pragma unroll
        for (int it = 0; it < 4; ++it) {            // B tile 32x128
            int s = tid + it * 256;
            int kk = s >> 5, cq = s & 31;
            *(float4*)&Bs[kk][cq * 4] = *(const float4*)&Wr[(size_t)(kb + kk) * DH + cq * 4];
        }
        __syncthreads();
        #pragma unroll 8
        for (int kk = 0; kk < 32; ++kk) {
            float4 a  = *(const float4*)&At[kk][ty * 4];
            float4 b0 = *(const float4*)&Bs[kk][tx * 8];
            float4 b1 = *(const float4*)&Bs[kk][tx * 8 + 4];
            float av[4] = {a.x, a.y, a.z, a.w};
            float bv[8] = {b0.x, b0.y, b0.z, b0.w, b1.x, b1.y, b1.z, b1.w};
            #pragma unroll
            for (int i = 0; i < 4; ++i)
                #pragma unroll
                for (int j = 0; j < 8; ++j)
                    acc[i][j] = fmaf(av[i], bv[j], acc[i][j]);
        }
    }

    if (r < NR) {
        unsigned short* base = xw + ((size_t)r * Nn + rowbase) * DH;
        #pragma unroll
        for (int i = 0; i < 4; ++i) {
            int row = ty * 4 + i;
            uint4 u;
            u.x = (unsigned)f2bf(acc[i][0]) | ((unsigned)f2bf(acc[i][1]) << 16);
            u.y = (unsigned)f2bf(acc[i][2]) | ((unsigned)f2bf(acc[i][3]) << 16);
            u.z = (unsigned)f2bf(acc[i][4]) | ((unsigned)f2bf(acc[i][5]) << 16);
            u.w = (unsigned)f2bf(acc[i][6]) | ((unsigned)f2bf(acc[i][7]) << 16);
            *(uint4*)(base + (size_t)row * DH + tx * 8) = u;
        }
    } else {
        float bv[8];
        #pragma unroll
        for (int j = 0; j < 8; ++j) bv[j] = bias1[tx * 8 + j];
        #pragma unroll
        for (int i = 0; i < 4; ++i) {
            int row = rowbase + ty * 4 + i;
            float4 o0 = {acc[i][0] + bv[0], acc[i][1] + bv[1], acc[i][2] + bv[2], acc[i][3] + bv[3]};
            float4 o1 = {acc[i][4] + bv[4], acc[i][5] + bv[5], acc[i][6] + bv[6], acc[i][7] + bv[7]};
            *(float4*)&h[(size_t)row * DH + tx * 8] = o0;
            *(float4*)&h[(size_t)row * DH + tx * 8 + 4] = o1;
        }
    }
}

// ---------- pass-1 aggregation: one wave per dst node ----------
// h[dst] += (1/deg) * sum_e xw[type_e][src_e]; also emit bf16 copy of h
__global__ __launch_bounds__(256) void k_agg1(const int* __restrict__ offsets,
                                              const unsigned* __restrict__ sorted,
                                              const unsigned* __restrict__ xw32,  // bf16x2 rows
                                              int Nn, float* __restrict__ h,
                                              unsigned* __restrict__ hbf) {
    int w = (blockIdx.x * blockDim.x + threadIdx.x) >> 6;
    if (w >= Nn) return;
    int lane = threadIdx.x & 63;
    int s = offsets[w], e = offsets[w + 1];
    float ax = 0.f, ay = 0.f;
    int p = s;
    for (; p + 1 < e; p += 2) {
        unsigned pk0 = sorted[p], pk1 = sorted[p + 1];
        unsigned u0 = xw32[((size_t)(pk0 >> 17) * Nn + (pk0 & 0x1FFFFu)) * 64 + lane];
        unsigned u1 = xw32[((size_t)(pk1 >> 17) * Nn + (pk1 & 0x1FFFFu)) * 64 + lane];
        ax += __uint_as_float(u0 << 16);
        ay += __uint_as_float(u0 & 0xffff0000u);
        ax += __uint_as_float(u1 << 16);
        ay += __uint_as_float(u1 & 0xffff0000u);
    }
    if (p < e) {
        unsigned pk0 = sorted[p];
        unsigned u0 = xw32[((size_t)(pk0 >> 17) * Nn + (pk0 & 0x1FFFFu)) * 64 + lane];
        ax += __uint_as_float(u0 << 16);
        ay += __uint_as_float(u0 & 0xffff0000u);
    }
    float invd = 1.0f / fmaxf((float)(e - s), 1.0f);
    float2 hv = *(float2*)&h[(size_t)w * DH + 2 * lane];
    hv.x += ax * invd;
    hv.y += ay * invd;
    *(float2*)&h[(size_t)w * DH + 2 * lane] = hv;
    hbf[(size_t)w * 64 + lane] = (unsigned)f2bf(hv.x) | ((unsigned)f2bf(hv.y) << 16);
}

// ---------- pass-2 aggregation: nbr[dst] = sum_e h[src_e] (bf16 gather, fp32 acc) ----------
__global__ __launch_bounds__(256) void k_agg2(const int* __restrict__ offsets,
                                              const unsigned* __restrict__ sorted,
                                              const unsigned* __restrict__ hbf,
                                              int Nn, float* __restrict__ nbr) {
    int w = (blockIdx.x * blockDim.x + threadIdx.x) >> 6;
    if (w >= Nn) return;
    int lane = threadIdx.x & 63;
    int s = offsets[w], e = offsets[w + 1];
    float ax = 0.f, ay = 0.f;
    int p = s;
    for (; p + 1 < e; p += 2) {
        unsigned pk0 = sorted[p], pk1 = sorted[p + 1];
        unsigned u0 = hbf[(size_t)(pk0 & 0x1FFFFu) * 64 + lane];
        unsigned u1 = hbf[(size_t)(pk1 & 0x1FFFFu) * 64 + lane];
        ax += __uint_as_float(u0 << 16);
        ay += __uint_as_float(u0 & 0xffff0000u);
        ax += __uint_as_float(u1 << 16);
        ay += __uint_as_float(u1 & 0xffff0000u);
    }
    if (p < e) {
        unsigned pk0 = sorted[p];
        unsigned u0 = hbf[(size_t)(pk0 & 0x1FFFFu) * 64 + lane];
        ax += __uint_as_float(u0 << 16);
        ay += __uint_as_float(u0 & 0xffff0000u);
    }
    float2 o = {ax, ay};
    *(float2*)&nbr[(size_t)w * DH + 2 * lane] = o;
}

// ---------- out = nbr@w_rel + h@w_root2 + bias2 ----------
__global__ __launch_bounds__(256) void k_gemm2(const float* __restrict__ nbr,
                                               const float* __restrict__ h,
                                               const float* __restrict__ wrel,
                                               const float* __restrict__ wroot2,
                                               const float* __restrict__ bias2,
                                               float* __restrict__ out) {
    __shared__ float At[32][68];
    __shared__ float Bs[32][132];
    const int tid = threadIdx.x;
    const int tx = tid & 15;
    const int ty = tid >> 4;
    const int rowbase = blockIdx.x * 64;

    float acc[4][8];
    #pragma unroll
    for (int i = 0; i < 4; ++i)
        #pragma unroll
        for (int j = 0; j < 8; ++j) acc[i][j] = 0.f;

    for (int kt = 0; kt < 8; ++kt) {
        const float* A = (kt < 4) ? nbr : h;
        const float* W = (kt < 4) ? wrel : wroot2;
        const int kb = (kt & 3) * 32;
        __syncthreads();
        #pragma unroll
        for (int it = 0; it < 2; ++it) {
            int s = tid + it * 256;
            int row = s >> 3, kq = s & 7;
            float4 v = *(const float4*)&A[(size_t)(rowbase + row) * DH + kb + kq * 4];
            At[kq * 4 + 0][row] = v.x;
            At[kq * 4 + 1][row] = v.y;
            At[kq * 4 + 2][row] = v.z;
            At[kq * 4 + 3][row] = v.w;
        }
        #pragma unroll
        for (int it = 0; it < 4; ++it) {
            int s = tid + it * 256;
            int kk = s >> 5, cq = s & 31;
            *(float4*)&Bs[kk][cq * 4] = *(const float4*)&W[(size_t)(kb + kk) * DH + cq * 4];
        }
        __syncthreads();
        #pragma unroll 8
        for (int kk = 0; kk < 32; ++kk) {
            float4 a  = *(const float4*)&At[kk][ty * 4];
            float4 b0 = *(const float4*)&Bs[kk][tx * 8];
            float4 b1 = *(const float4*)&Bs[kk][tx * 8 + 4];
            float av[4] = {a.x, a.y, a.z, a.w};
            float bv[8] = {b0.x, b0.y, b0.z, b0.w, b1.x, b1.y, b1.z, b1.w};
            #pragma unroll
            for (int i = 0; i < 4; ++i)
                #pragma unroll
                for (int j = 0; j < 8; ++j)
                    acc[i][j] = fmaf(av[i], bv[j], acc[i][j]);
        }
    }

    float bv[8];
    #pragma unroll
    for (int j = 0; j < 8; ++j) bv[j] = bias2[tx * 8 + j];
    #pragma unroll
    for (int i = 0; i < 4; ++i) {
        int row = rowbase + ty * 4 + i;
        float4 o0 = {acc[i][0] + bv[0], acc[i][1] + bv[1], acc[i][2] + bv[2], acc[i][3] + bv[3]};
        float4 o1 = {acc[i][4] + bv[4], acc[i][5] + bv[5], acc[i][6] + bv[6], acc[i][7] + bv[7]};
        *(float4*)&out[(size_t)row * DH + tx * 8] = o0;
        *(float4*)&out[(size_t)row * DH + tx * 8 + 4] = o1;
    }
}

extern "C" void kernel_launch(void* const* d_in, const int* in_sizes, int n_in,
                              void* d_out, int out_size, void* d_ws, size_t ws_size,
                              hipStream_t stream) {
    const float* x      = (const float*)d_in[0];
    const int*   eidx   = (const int*)d_in[1];
    // d_in[2] = edge_norm: unused by the reference computation
    const int*   etype  = (const int*)d_in[3];
    const float* basis  = (const float*)d_in[4];
    const float* comp   = (const float*)d_in[5];
    const float* root   = (const float*)d_in[6];
    const float* bias1  = (const float*)d_in[7];
    const float* wrel   = (const float*)d_in[8];
    const float* wroot2 = (const float*)d_in[9];
    const float* bias2  = (const float*)d_in[10];
    float* out = (float*)d_out;

    const int N = in_sizes[0] / DH;    // 40000
    const int E = in_sizes[3];         // 640000
    const int* srcA = eidx;
    const int* dstA = eidx + E;

    char* ws = (char*)d_ws;
    size_t off = 0;
    auto alloc = [&](size_t bytes) -> void* {
        void* p = (void*)(ws + off);
        off += (bytes + 255) & ~(size_t)255;
        return p;
    };
    int* deg          = (int*)alloc((size_t)N * 4);          // N*4 is 256-aligned (40000*4)
    int* cursor       = (int*)alloc((size_t)N * 4);          // adjacent to deg
    int* offsets      = (int*)alloc((size_t)(N + 1) * 4);
    int* partial      = (int*)alloc(256 * 4);
    unsigned* sorted  = (unsigned*)alloc((size_t)E * 4);
    float* wall       = (float*)alloc((size_t)(NR + 1) * DH * DH * 4);
    unsigned short* xw = (unsigned short*)alloc((size_t)NR * N * DH * 2);
    float* h          = (float*)alloc((size_t)N * DH * 4);
    unsigned* hbf     = (unsigned*)alloc((size_t)N * (DH / 2) * 4);
    float* nbr        = (float*)alloc((size_t)N * DH * 4);
    (void)ws_size; (void)n_in; (void)out_size;

    hipMemsetAsync(deg, 0, (size_t)N * 8, stream);  // deg + cursor (contiguous)

    k_wall<<<dim3(DH, NR + 1), DH, 0, stream>>>(comp, basis, root, wall);
    k_hist<<<(E + 255) / 256, 256, 0, stream>>>(dstA, E, deg);

    const int totn = N + 1;
    const int nsb = (totn + 1023) / 1024;
    k_scan1<<<nsb, 1024, 0, stream>>>(deg, N, totn, offsets, partial);
    k_scan2<<<1, 64, 0, stream>>>(partial, nsb);
    k_scan3<<<nsb, 1024, 0, stream>>>(offsets, partial, totn);
    k_scatter<<<(E + 255) / 256, 256, 0, stream>>>(srcA, dstA, etype, E, offsets, cursor, sorted);

    k_gemm1<<<dim3(N / 64, NR + 1), 256, 0, stream>>>(x, wall, bias1, N, xw, h);
    k_agg1<<<(N * 64) / 256, 256, 0, stream>>>(offsets, sorted, (const unsigned*)xw, N, h, hbf);
    k_agg2<<<(N * 64) / 256, 256, 0, stream>>>(offsets, sorted, hbf, N, nbr);
    k_gemm2<<<N / 64, 256, 0, stream>>>(nbr, h, wrel, wroot2, bias2, out);
}

// Round 2
// 294.517 us; speedup vs baseline: 1.5637x; 1.5637x over previous
//
#include <hip/hip_runtime.h>
#include <stdint.h>

#define DH 128   // D_IN == H == 128
#define NB 30    // num bases
#define NR 8     // num relations

typedef short bf16x8 __attribute__((ext_vector_type(8)));   // 8 bf16 = 4 VGPRs
typedef float f32x4 __attribute__((ext_vector_type(4)));

static __device__ __forceinline__ unsigned short f2bf(float f) {
    unsigned u = __float_as_uint(f);
    u += 0x7fffu + ((u >> 16) & 1u);   // round-to-nearest-even
    return (unsigned short)(u >> 16);
}

// ---------- X fp32 -> bf16 ----------
__global__ __launch_bounds__(256) void k_cvtx(const float* __restrict__ x,
                                              unsigned short* __restrict__ xbf, int n4) {
    int i = blockIdx.x * blockDim.x + threadIdx.x;
    if (i < n4) {
        float4 v = ((const float4*)x)[i];
        ushort4 u;
        u.x = f2bf(v.x); u.y = f2bf(v.y); u.z = f2bf(v.z); u.w = f2bf(v.w);
        ((ushort4*)xbf)[i] = u;
    }
}

// ---------- wallT[r][o][i] = (sum_b comp[r,b]*basis[b,i,o]) as bf16 (r==8 -> root) ----------
__global__ __launch_bounds__(128) void k_wall(const float* __restrict__ comp,
                                              const float* __restrict__ basis,
                                              const float* __restrict__ root,
                                              unsigned short* __restrict__ wallT) {
    int o = threadIdx.x;    // 0..127
    int i = blockIdx.x;     // 0..127
    int r = blockIdx.y;     // 0..8
    float s;
    if (r == NR) {
        s = root[i * DH + o];
    } else {
        s = 0.f;
        #pragma unroll
        for (int b = 0; b < NB; ++b)
            s += comp[r * NB + b] * basis[((size_t)b * DH + i) * DH + o];
    }
    wallT[((size_t)r * DH + o) * DH + i] = f2bf(s);   // transposed [n][k]
}

// ---------- WT2[p][n][k] = (p? wroot2 : wrel)[k][n] as bf16 ----------
__global__ __launch_bounds__(128) void k_wt2(const float* __restrict__ wrel,
                                             const float* __restrict__ wroot2,
                                             unsigned short* __restrict__ WT2) {
    int n = threadIdx.x; int k = blockIdx.x; int p = blockIdx.y;
    const float* W = p ? wroot2 : wrel;
    WT2[((size_t)p * DH + n) * DH + k] = f2bf(W[k * DH + n]);
}

// ---------- CSR build ----------
__global__ void k_hist(const int* __restrict__ dst, int E, int* __restrict__ deg) {
    int e = blockIdx.x * blockDim.x + threadIdx.x;
    if (e < E) atomicAdd(&deg[dst[e]], 1);
}

__global__ __launch_bounds__(1024) void k_scan1(const int* __restrict__ deg, int n, int total_n,
                                                int* __restrict__ offsets, int* __restrict__ partial) {
    __shared__ int s[1024];
    int tid = threadIdx.x;
    int i = blockIdx.x * 1024 + tid;
    int v = (i < n) ? deg[i] : 0;
    s[tid] = v;
    __syncthreads();
    for (int off = 1; off < 1024; off <<= 1) {
        int t = (tid >= off) ? s[tid - off] : 0;
        __syncthreads();
        s[tid] += t;
        __syncthreads();
    }
    if (i < total_n) offsets[i] = s[tid] - v;   // exclusive
    if (tid == 1023) partial[blockIdx.x] = s[1023];
}

__global__ void k_scan2(int* __restrict__ partial, int nb) {
    if (threadIdx.x == 0) {
        int run = 0;
        for (int b = 0; b < nb; ++b) { int t = partial[b]; partial[b] = run; run += t; }
    }
}

__global__ __launch_bounds__(1024) void k_scan3(int* __restrict__ offsets,
                                                const int* __restrict__ partial, int total_n) {
    int i = blockIdx.x * 1024 + threadIdx.x;
    if (i < total_n) offsets[i] += partial[blockIdx.x];
}

__global__ void k_scatter(const int* __restrict__ src, const int* __restrict__ dstA,
                          const int* __restrict__ etype, int E,
                          const int* __restrict__ offsets, int* __restrict__ cursor,
                          unsigned* __restrict__ sorted) {
    int e = blockIdx.x * blockDim.x + threadIdx.x;
    if (e >= E) return;
    int d = dstA[e];
    int pos = offsets[d] + atomicAdd(&cursor[d], 1);
    sorted[pos] = (unsigned)src[e] | ((unsigned)etype[e] << 17);  // src<2^17, type<8
}

// ---------- MFMA GEMM1: 128x128 tile, K=128, grid (ceil(N/128), 9) ----------
// r<8: xw[r] = Xbf @ W_r  (bf16 out, canonical rows via LDS repack)
// r==8: h = Xbf @ root + bias1 (fp32 out)
__global__ __launch_bounds__(256) void k_gemm1m(const unsigned short* __restrict__ Xbf,
                                                const unsigned short* __restrict__ wallT,
                                                const float* __restrict__ bias1,
                                                int Nn,
                                                unsigned short* __restrict__ xw,
                                                float* __restrict__ h) {
    __shared__ __align__(16) unsigned short As[128][136];  // [m][k], +8 pad
    __shared__ __align__(16) unsigned short Bs[128][136];  // [n][k], +8 pad
    const int tid = threadIdx.x;
    const int wave = tid >> 6, lane = tid & 63;
    const int r = blockIdx.y;
    const int rowbase = blockIdx.x * 128;
    const unsigned short* WT = wallT + (size_t)r * DH * DH;

    // stage A (128 rows x 256B) and B (128 x 256B)
    #pragma unroll
    for (int it = 0; it < 8; ++it) {
        int c = it * 256 + tid;
        int row = c >> 4, col = c & 15;
        int rg = rowbase + row; if (rg >= Nn) rg = Nn - 1;
        *(uint4*)&As[row][col * 8] = *(const uint4*)&Xbf[(size_t)rg * DH + col * 8];
        *(uint4*)&Bs[row][col * 8] = *(const uint4*)&WT[(size_t)row * DH + col * 8];
    }
    __syncthreads();

    f32x4 acc[2][8];
    #pragma unroll
    for (int mt = 0; mt < 2; ++mt)
        #pragma unroll
        for (int nt = 0; nt < 8; ++nt) acc[mt][nt] = (f32x4)0.f;

    const int lq = lane >> 4, lr = lane & 15;
    #pragma unroll
    for (int ks = 0; ks < 4; ++ks) {
        const int ko = ks * 32 + lq * 8;
        bf16x8 a0 = *(const bf16x8*)&As[wave * 32 + lr][ko];
        bf16x8 a1 = *(const bf16x8*)&As[wave * 32 + 16 + lr][ko];
        #pragma unroll
        for (int nt = 0; nt < 8; ++nt) {
            bf16x8 b = *(const bf16x8*)&Bs[nt * 16 + lr][ko];
            acc[0][nt] = __builtin_amdgcn_mfma_f32_16x16x32_bf16(a0, b, acc[0][nt], 0, 0, 0);
            acc[1][nt] = __builtin_amdgcn_mfma_f32_16x16x32_bf16(a1, b, acc[1][nt], 0, 0, 0);
        }
    }

    if (r < NR) {
        // repack C-layout (col=lane&15, row=(lane>>4)*4+reg) -> canonical bf16 rows via As
        #pragma unroll
        for (int mt = 0; mt < 2; ++mt)
            #pragma unroll
            for (int nt = 0; nt < 8; ++nt)
                #pragma unroll
                for (int reg = 0; reg < 4; ++reg) {
                    int ml = wave * 32 + mt * 16 + lq * 4 + reg;     // own slab only
                    As[ml][nt * 16 + lr] = f2bf(acc[mt][nt][reg]);
                }
        __syncthreads();
        unsigned short* dst = xw + ((size_t)r * Nn + rowbase) * DH;
        #pragma unroll
        for (int it = 0; it < 8; ++it) {
            int c = it * 256 + tid;
            int row = c >> 4, col = c & 15;
            if (rowbase + row < Nn)
                *(uint4*)&dst[(size_t)row * DH + col * 8] = *(uint4*)&As[row][col * 8];
        }
    } else {
        float bv[8];
        #pragma unroll
        for (int nt = 0; nt < 8; ++nt) bv[nt] = bias1[nt * 16 + lr];
        #pragma unroll
        for (int mt = 0; mt < 2; ++mt)
            #pragma unroll
            for (int nt = 0; nt < 8; ++nt)
                #pragma unroll
                for (int reg = 0; reg < 4; ++reg) {
                    int m = rowbase + wave * 32 + mt * 16 + lq * 4 + reg;
                    if (m < Nn) h[(size_t)m * DH + nt * 16 + lr] = acc[mt][nt][reg] + bv[nt];
                }
    }
}

// ---------- pass-1 aggregation: one wave per dst node ----------
// hbf[dst] = bf16( h[dst] + (1/deg) * sum_e xw[type_e][src_e] )
__global__ __launch_bounds__(256) void k_agg1(const int* __restrict__ offsets,
                                              const unsigned* __restrict__ sorted,
                                              const unsigned* __restrict__ xw32,
                                              int Nn, const float* __restrict__ h,
                                              unsigned* __restrict__ hbf) {
    int w = (blockIdx.x * blockDim.x + threadIdx.x) >> 6;
    if (w >= Nn) return;
    int lane = threadIdx.x & 63;
    int s = offsets[w], e = offsets[w + 1];
    float ax = 0.f, ay = 0.f;
    int p = s;
    for (; p + 1 < e; p += 2) {
        unsigned pk0 = sorted[p], pk1 = sorted[p + 1];
        unsigned u0 = xw32[((size_t)(pk0 >> 17) * Nn + (pk0 & 0x1FFFFu)) * 64 + lane];
        unsigned u1 = xw32[((size_t)(pk1 >> 17) * Nn + (pk1 & 0x1FFFFu)) * 64 + lane];
        ax += __uint_as_float(u0 << 16);
        ay += __uint_as_float(u0 & 0xffff0000u);
        ax += __uint_as_float(u1 << 16);
        ay += __uint_as_float(u1 & 0xffff0000u);
    }
    if (p < e) {
        unsigned pk0 = sorted[p];
        unsigned u0 = xw32[((size_t)(pk0 >> 17) * Nn + (pk0 & 0x1FFFFu)) * 64 + lane];
        ax += __uint_as_float(u0 << 16);
        ay += __uint_as_float(u0 & 0xffff0000u);
    }
    float invd = 1.0f / fmaxf((float)(e - s), 1.0f);
    float2 hv = *(const float2*)&h[(size_t)w * DH + 2 * lane];
    float hx = hv.x + ax * invd;
    float hy = hv.y + ay * invd;
    hbf[(size_t)w * 64 + lane] = (unsigned)f2bf(hx) | ((unsigned)f2bf(hy) << 16);
}

// ---------- pass-2 aggregation: nbrbf[dst] = bf16( sum_e h[src_e] ) ----------
__global__ __launch_bounds__(256) void k_agg2(const int* __restrict__ offsets,
                                              const unsigned* __restrict__ sorted,
                                              const unsigned* __restrict__ hbf,
                                              int Nn, unsigned* __restrict__ nbrbf) {
    int w = (blockIdx.x * blockDim.x + threadIdx.x) >> 6;
    if (w >= Nn) return;
    int lane = threadIdx.x & 63;
    int s = offsets[w], e = offsets[w + 1];
    float ax = 0.f, ay = 0.f;
    int p = s;
    for (; p + 1 < e; p += 2) {
        unsigned pk0 = sorted[p], pk1 = sorted[p + 1];
        unsigned u0 = hbf[(size_t)(pk0 & 0x1FFFFu) * 64 + lane];
        unsigned u1 = hbf[(size_t)(pk1 & 0x1FFFFu) * 64 + lane];
        ax += __uint_as_float(u0 << 16);
        ay += __uint_as_float(u0 & 0xffff0000u);
        ax += __uint_as_float(u1 << 16);
        ay += __uint_as_float(u1 & 0xffff0000u);
    }
    if (p < e) {
        unsigned pk0 = sorted[p];
        unsigned u0 = hbf[(size_t)(pk0 & 0x1FFFFu) * 64 + lane];
        ax += __uint_as_float(u0 << 16);
        ay += __uint_as_float(u0 & 0xffff0000u);
    }
    nbrbf[(size_t)w * 64 + lane] = (unsigned)f2bf(ax) | ((unsigned)f2bf(ay) << 16);
}

// ---------- MFMA GEMM2: out = nbr@w_rel + h@w_root2 + bias2 (K=256 in 2 phases) ----------
__global__ __launch_bounds__(256) void k_gemm2m(const unsigned short* __restrict__ nbrbf,
                                                const unsigned short* __restrict__ hbf,
                                                const unsigned short* __restrict__ WT2,
                                                const float* __restrict__ bias2,
                                                int Nn, float* __restrict__ out) {
    __shared__ __align__(16) unsigned short As[128][136];
    __shared__ __align__(16) unsigned short Bs[128][136];
    const int tid = threadIdx.x;
    const int wave = tid >> 6, lane = tid & 63;
    const int rowbase = blockIdx.x * 128;
    const int lq = lane >> 4, lr = lane & 15;

    f32x4 acc[2][8];
    #pragma unroll
    for (int mt = 0; mt < 2; ++mt)
        #pragma unroll
        for (int nt = 0; nt < 8; ++nt) acc[mt][nt] = (f32x4)0.f;

    for (int ph = 0; ph < 2; ++ph) {
        const unsigned short* A = ph ? hbf : nbrbf;
        const unsigned short* WT = WT2 + (size_t)ph * DH * DH;
        if (ph) __syncthreads();
        #pragma unroll
        for (int it = 0; it < 8; ++it) {
            int c = it * 256 + tid;
            int row = c >> 4, col = c & 15;
            int rg = rowbase + row; if (rg >= Nn) rg = Nn - 1;
            *(uint4*)&As[row][col * 8] = *(const uint4*)&A[(size_t)rg * DH + col * 8];
            *(uint4*)&Bs[row][col * 8] = *(const uint4*)&WT[(size_t)row * DH + col * 8];
        }
        __syncthreads();
        #pragma unroll
        for (int ks = 0; ks < 4; ++ks) {
            const int ko = ks * 32 + lq * 8;
            bf16x8 a0 = *(const bf16x8*)&As[wave * 32 + lr][ko];
            bf16x8 a1 = *(const bf16x8*)&As[wave * 32 + 16 + lr][ko];
            #pragma unroll
            for (int nt = 0; nt < 8; ++nt) {
                bf16x8 b = *(const bf16x8*)&Bs[nt * 16 + lr][ko];
                acc[0][nt] = __builtin_amdgcn_mfma_f32_16x16x32_bf16(a0, b, acc[0][nt], 0, 0, 0);
                acc[1][nt] = __builtin_amdgcn_mfma_f32_16x16x32_bf16(a1, b, acc[1][nt], 0, 0, 0);
            }
        }
    }

    float bv[8];
    #pragma unroll
    for (int nt = 0; nt < 8; ++nt) bv[nt] = bias2[nt * 16 + lr];
    #pragma unroll
    for (int mt = 0; mt < 2; ++mt)
        #pragma unroll
        for (int nt = 0; nt < 8; ++nt)
            #pragma unroll
            for (int reg = 0; reg < 4; ++reg) {
                int m = rowbase + wave * 32 + mt * 16 + lq * 4 + reg;
                if (m < Nn) out[(size_t)m * DH + nt * 16 + lr] = acc[mt][nt][reg] + bv[nt];
            }
}

extern "C" void kernel_launch(void* const* d_in, const int* in_sizes, int n_in,
                              void* d_out, int out_size, void* d_ws, size_t ws_size,
                              hipStream_t stream) {
    const float* x      = (const float*)d_in[0];
    const int*   eidx   = (const int*)d_in[1];
    // d_in[2] = edge_norm: unused by the reference computation
    const int*   etype  = (const int*)d_in[3];
    const float* basis  = (const float*)d_in[4];
    const float* comp   = (const float*)d_in[5];
    const float* root   = (const float*)d_in[6];
    const float* bias1  = (const float*)d_in[7];
    const float* wrel   = (const float*)d_in[8];
    const float* wroot2 = (const float*)d_in[9];
    const float* bias2  = (const float*)d_in[10];
    float* out = (float*)d_out;

    const int N = in_sizes[0] / DH;    // 40000
    const int E = in_sizes[3];         // 640000
    const int* srcA = eidx;
    const int* dstA = eidx + E;

    char* ws = (char*)d_ws;
    size_t off = 0;
    auto alloc = [&](size_t bytes) -> void* {
        void* p = (void*)(ws + off);
        off += (bytes + 255) & ~(size_t)255;
        return p;
    };
    int* deg           = (int*)alloc((size_t)N * 4);      // N*4 divisible by 256
    int* cursor        = (int*)alloc((size_t)N * 4);      // adjacent to deg
    int* offsets       = (int*)alloc((size_t)(N + 1) * 4);
    int* partial       = (int*)alloc(256 * 4);
    unsigned* sorted   = (unsigned*)alloc((size_t)E * 4);
    unsigned short* wallT = (unsigned short*)alloc((size_t)(NR + 1) * DH * DH * 2);
    unsigned short* WT2   = (unsigned short*)alloc((size_t)2 * DH * DH * 2);
    unsigned short* Xbf   = (unsigned short*)alloc((size_t)N * DH * 2);
    unsigned short* xw    = (unsigned short*)alloc((size_t)NR * N * DH * 2);
    float* h           = (float*)alloc((size_t)N * DH * 4);
    unsigned* hbf      = (unsigned*)alloc((size_t)N * (DH / 2) * 4);
    unsigned* nbrbf    = (unsigned*)alloc((size_t)N * (DH / 2) * 4);
    (void)ws_size; (void)n_in; (void)out_size;

    hipMemsetAsync(deg, 0, (size_t)N * 8, stream);  // deg + cursor (contiguous)

    k_cvtx<<<(N * DH / 4 + 255) / 256, 256, 0, stream>>>(x, Xbf, N * DH / 4);
    k_wall<<<dim3(DH, NR + 1), DH, 0, stream>>>(comp, basis, root, wallT);
    k_wt2<<<dim3(DH, 2), DH, 0, stream>>>(wrel, wroot2, WT2);
    k_hist<<<(E + 255) / 256, 256, 0, stream>>>(dstA, E, deg);

    const int totn = N + 1;
    const int nsb = (totn + 1023) / 1024;
    k_scan1<<<nsb, 1024, 0, stream>>>(deg, N, totn, offsets, partial);
    k_scan2<<<1, 64, 0, stream>>>(partial, nsb);
    k_scan3<<<nsb, 1024, 0, stream>>>(offsets, partial, totn);
    k_scatter<<<(E + 255) / 256, 256, 0, stream>>>(srcA, dstA, etype, E, offsets, cursor, sorted);

    const int gx = (N + 127) / 128;
    k_gemm1m<<<dim3(gx, NR + 1), 256, 0, stream>>>(Xbf, wallT, bias1, N, xw, h);
    k_agg1<<<(N * 64) / 256, 256, 0, stream>>>(offsets, sorted, (const unsigned*)xw, N, h, hbf);
    k_agg2<<<(N * 64) / 256, 256, 0, stream>>>(offsets, sorted, hbf, N, (unsigned*)nbrbf);
    k_gemm2m<<<gx, 256, 0, stream>>>((const unsigned short*)nbrbf, (const unsigned short*)hbf,
                                     WT2, bias2, N, out);
}